// Round 4
// baseline (869.719 us; speedup 1.0000x reference)
//
#include <hip/hip_runtime.h>

typedef unsigned short u16;
typedef unsigned int u32;
typedef __attribute__((ext_vector_type(4))) float f32x4;
typedef __attribute__((ext_vector_type(8))) short bf16x8;

#define B_ 4
#define S_ 4096
#define H_ 16
#define DH_ 64
#define R_ 256
#define DM_ 1024
#define M_ 16384
#define ROWSTR 1024

__device__ __forceinline__ float bf2f(u16 u) {
  union { u32 i; float f; } v; v.i = ((u32)u) << 16; return v.f;
}
__device__ __forceinline__ u16 f2bf(float f) {
  union { float f; u32 i; } v; v.f = f;
  u32 x = v.i;
  return (u16)((x + 0x7FFFu + ((x >> 16) & 1u)) >> 16);
}
// async global->LDS, 16B/lane; dest = wave-uniform base + lane*16 (verified m97 pattern)
__device__ __forceinline__ void lds_load16(const void* g, void* l) {
  __builtin_amdgcn_global_load_lds((__attribute__((address_space(1))) void*)(g),
                                   (__attribute__((address_space(3))) void*)(l), 16, 0, 0);
}
__device__ __forceinline__ int vt_idx(int dv, int s) {  // XOR-swizzled [64][64]
  return dv * 64 + (s ^ (dv & 0x38));
}

// ---------------- dtype probe: bf16 vs f32 underlying data ----------------
__global__ __launch_bounds__(256) void dtype_probe_k(const u16* __restrict__ q,
                                                     int* __restrict__ flag) {
  __shared__ int cnt_s;
  int tid = threadIdx.x;
  if (tid == 0) cnt_s = 0;
  __syncthreads();
  int c = 0;
  for (int i = tid; i < 1024; i += 256) {
    u32 e = ((u32)q[i] >> 7) & 0xFF;
    c += (e >= 134) ? 1 : 0;
  }
  atomicAdd(&cnt_s, c);
  __syncthreads();
  if (tid == 0) flag[0] = (cnt_s > 32) ? 1 : 0;
}

// ---------------- split input [16M elems] -> bf16 hi(/lo) planes ----------------
template <int WLO>
__global__ __launch_bounds__(256) void split_k(const void* __restrict__ src,
                                               u16* __restrict__ hi, u16* __restrict__ lo,
                                               const int* __restrict__ flag) {
  const bool f32m = flag[0] != 0;
  size_t i = ((size_t)blockIdx.x * 256 + threadIdx.x) * 8;
  if (f32m) {
    f32x4 a = *(const f32x4*)((const float*)src + i);
    f32x4 b = *(const f32x4*)((const float*)src + i + 4);
    bf16x8 h, l;
    for (int e = 0; e < 4; ++e) {
      u16 ha = f2bf(a[e]); h[e] = (short)ha; l[e] = (short)f2bf(a[e] - bf2f(ha));
      u16 hb = f2bf(b[e]); h[4 + e] = (short)hb; l[4 + e] = (short)f2bf(b[e] - bf2f(hb));
    }
    *(bf16x8*)(hi + i) = h;
    if (WLO) *(bf16x8*)(lo + i) = l;
  } else {
    bf16x8 h = *(const bf16x8*)((const u16*)src + i);
    *(bf16x8*)(hi + i) = h;
    if (WLO) {
      bf16x8 z = {0, 0, 0, 0, 0, 0, 0, 0};
      *(bf16x8*)(lo + i) = z;
    }
  }
}

// ---------------- transpose+convert 4x [1024][1024] weights -> bf16 hi/lo ----------------
// lo planes written only for z<2 (Wq,Wk); Wv/Wo lo are never consumed.
__global__ __launch_bounds__(256) void transpose4_k(
    const void* __restrict__ s0, const void* __restrict__ s1,
    const void* __restrict__ s2, const void* __restrict__ s3,
    u16* __restrict__ dh0, u16* __restrict__ dl0, u16* __restrict__ dh1, u16* __restrict__ dl1,
    u16* __restrict__ dh2, u16* __restrict__ dl2, u16* __restrict__ dh3, u16* __restrict__ dl3,
    const int* __restrict__ flag) {
  __shared__ float tile[32][33];
  const bool f32m = flag[0] != 0;
  int z = blockIdx.z;
  const void* src = (z == 0) ? s0 : (z == 1) ? s1 : (z == 2) ? s2 : s3;
  u16* dh = (z == 0) ? dh0 : (z == 1) ? dh1 : (z == 2) ? dh2 : dh3;
  u16* dl = (z == 0) ? dl0 : (z == 1) ? dl1 : (z == 2) ? dl2 : dl3;
  int tx = threadIdx.x, ty = threadIdx.y;
  int x0 = blockIdx.x * 32, y0 = blockIdx.y * 32;
  for (int i = ty; i < 32; i += 8) {
    size_t idx = (size_t)(y0 + i) * DM_ + x0 + tx;
    tile[i][tx] = f32m ? ((const float*)src)[idx] : bf2f(((const u16*)src)[idx]);
  }
  __syncthreads();
  for (int i = ty; i < 32; i += 8) {
    float t = tile[tx][i];
    u16 hi = f2bf(t);
    size_t o = (size_t)(x0 + i) * DM_ + y0 + tx;
    dh[o] = hi;
    if (z < 2) dl[o] = f2bf(t - bf2f(hi));
  }
}

// ---------------- convert proj [256*64] -> hi/lo bf16 ----------------
__global__ __launch_bounds__(256) void projcvt_k(const void* __restrict__ p,
                                                 u16* __restrict__ ph, u16* __restrict__ pl,
                                                 const int* __restrict__ flag) {
  const bool f32m = flag[0] != 0;
  int i = blockIdx.x * 256 + threadIdx.x;
  if (i < R_ * DH_) {
    float t = f32m ? ((const float*)p)[i] : bf2f(((const u16*)p)[i]);
    u16 hi = f2bf(t);
    ph[i] = hi;
    pl[i] = f2bf(t - bf2f(hi));
  }
}

// ---------------- 128x128-tile GEMM, C = A[M,K]*Bt[N,K]^T + bias ----------------
// PREC 3 runs an extended K' = 3K with per-K-tile plane selection
//   seg0:(Ah,Bh)  seg1:(Ah,Bl)  seg2:(Al,Bh)   == hh + hl + lh
// so LDS stays 2 planes (32 KB) -> ~4 blk/CU, the measured m97/m103 shape.
// OUTMODE: 0 bf16; 1 hi/lo pair + fused diag (Sum q^2 * 0.0625); 2 final.
template <int PREC, int OUTMODE>
__global__ __launch_bounds__(256) void gemm_k(
    const u16* __restrict__ Ah, const u16* __restrict__ Al,
    const u16* __restrict__ Bth, const u16* __restrict__ Btl,
    const void* __restrict__ bias, void* __restrict__ C, u16* __restrict__ Clo,
    float* __restrict__ diag, const int* __restrict__ flag) {
  __shared__ __attribute__((aligned(16))) u16 pool[2 * 2 * 4096];  // 32 KB, dbuf x (A,B)
  const bool f32m = flag[0] != 0;
  const int K = DM_, N = DM_;
  constexpr int KT = (PREC == 3) ? 96 : 32;  // K-tiles of 32
  const int tid = threadIdx.x, wave = tid >> 6, lane = tid & 63;
  const int lr = lane & 15, qd = lane >> 4;
  const int bm = blockIdx.x, bn = blockIdx.y;
  const int m0 = (wave & 1) * 64, n0 = (wave >> 1) * 64;
  const u16* Abh = Ah + (size_t)bm * 128 * K;
  const u16* Bbh = Bth + (size_t)bn * 128 * K;
  const u16* Abl = (PREC == 3) ? Al + (size_t)bm * 128 * K : nullptr;
  const u16* Bbl = (PREC == 3) ? Btl + (size_t)bn * 128 * K : nullptr;
  f32x4 zero = {0.f, 0.f, 0.f, 0.f};
  f32x4 acc[4][4];
  for (int i = 0; i < 4; ++i) for (int j = 0; j < 4; ++j) acc[i][j] = zero;

#define GEMM_STAGE(bf, t)                                              \
  do {                                                                 \
    int seg_ = (PREC == 3) ? ((t) >> 5) : 0;                           \
    int kk_ = ((t) & 31) * 32;                                         \
    const u16* Ap_ = (seg_ == 2) ? Abl : Abh;                          \
    const u16* Bp_ = (seg_ == 1) ? Bbl : Bbh;                          \
    u16* Ph_ = pool + (bf) * 8192;                                     \
    for (int t_ = 0; t_ < 2; ++t_) {                                   \
      int c_ = wave + t_ * 4;                                          \
      int row_ = c_ * 16 + (lane >> 2);                                \
      int kc_ = (lane & 3) * 8;                                        \
      size_t go_ = (size_t)row_ * K + kk_ + kc_;                       \
      lds_load16(Ap_ + go_, (void*)&Ph_[c_ * 512]);                    \
      lds_load16(Bp_ + go_, (void*)&Ph_[4096 + c_ * 512]);             \
    }                                                                  \
  } while (0)

  GEMM_STAGE(0, 0);
  int cur = 0;
  for (int t = 0; t < KT; ++t) {
    __syncthreads();  // drains vmcnt(0): buf[cur] staged; prev reads of buf[cur^1] done
    if (t + 1 < KT) GEMM_STAGE(cur ^ 1, t + 1);
    const u16* Ash = pool + cur * 8192;
    const u16* Bsh = Ash + 4096;
    bf16x8 ah[4], bh[4];
    for (int i = 0; i < 4; ++i) ah[i] = *(const bf16x8*)&Ash[(m0 + i * 16 + lr) * 32 + qd * 8];
    for (int j = 0; j < 4; ++j) bh[j] = *(const bf16x8*)&Bsh[(n0 + j * 16 + lr) * 32 + qd * 8];
    for (int i = 0; i < 4; ++i)
      for (int j = 0; j < 4; ++j)
        acc[i][j] = __builtin_amdgcn_mfma_f32_16x16x32_bf16(ah[i], bh[j], acc[i][j], 0, 0, 0);
    cur ^= 1;
  }
#undef GEMM_STAGE
  float dq[16];
  if (OUTMODE == 1)
    for (int t = 0; t < 16; ++t) dq[t] = 0.f;
  for (int j = 0; j < 4; ++j) {
    int n = bn * 128 + n0 + j * 16 + lr;
    float bv = f32m ? ((const float*)bias)[n] : bf2f(((const u16*)bias)[n]);
    for (int i = 0; i < 4; ++i) {
      int mr = bm * 128 + m0 + i * 16 + qd * 4;
      for (int r2 = 0; r2 < 4; ++r2) {
        float x = acc[i][j][r2] + bv;
        size_t o = (size_t)(mr + r2) * N + n;
        if (OUTMODE == 0) {
          ((u16*)C)[o] = f2bf(x);
        } else if (OUTMODE == 1) {
          dq[i * 4 + r2] += x * x;
          u16 hi = f2bf(x);
          ((u16*)C)[o] = hi;
          Clo[o] = f2bf(x - bf2f(hi));
        } else {
          if (f32m) ((float*)C)[o] = x;
          else ((u16*)C)[o] = f2bf(x);
        }
      }
    }
  }
  if (OUTMODE == 1) {
    // each (i,r2) row: lanes lr*{j} cover all 64 dh of head h -> shfl-reduce over lr
    int h = (bn * 128 + n0) >> 6;
    for (int t = 0; t < 16; ++t) {
      float v = dq[t];
      v += __shfl_xor(v, 1, 64); v += __shfl_xor(v, 2, 64);
      v += __shfl_xor(v, 4, 64); v += __shfl_xor(v, 8, 64);
      if (lr == 0) {
        int mrow = bm * 128 + m0 + (t >> 2) * 16 + qd * 4 + (t & 3);
        diag[(size_t)mrow * H_ + h] = 0.0625f * v;
      }
    }
  }
}

// ---------------- kv accumulation (online-max; feat_max pass eliminated) ----------------
// Per block: running chunk max mr; acc/k1 rescaled by exp(mr_old-mr_new) on growth.
// Outputs unnormalized: pkv = Sum exp(a-d-mr) x v, pk1 = Sum exp, pvs = Sum v, pmc = mr.
// Final scaling (ratio, 1e-4 regularizer, global max) applied in kv_reduce.
__global__ __launch_bounds__(256) void kv_accum_k(
    const u16* __restrict__ khi, const u16* __restrict__ klo,
    const u16* __restrict__ vv,
    const u16* __restrict__ ph, const u16* __restrict__ pl,
    const float* __restrict__ diagk,
    float* __restrict__ pkv, float* __restrict__ pk1,
    float* __restrict__ pvs, float* __restrict__ pmc, int ipb) {
  __shared__ __attribute__((aligned(16))) u16 pool[256 * 72];  // kth|ktl then khatT then fbuf
  __shared__ __attribute__((aligned(16))) u16 vTh[64 * 64];
  __shared__ float diagl[64];
  __shared__ float red[4];
  u16* kth = pool;
  u16* ktl = pool + 4096;
  u16* khatT = pool;
  const int tid = threadIdx.x, wave = tid >> 6, lane = tid & 63;
  const int lr = lane & 15, qd = lane >> 4;
  int bid = blockIdx.x;
  int bh = bid & 63, c = bid >> 6;
  int b = bh >> 4, h = bh & 15;
  const float nrm = 0.3535533905932738f;
  size_t base0 = (((size_t)b * S_ + (size_t)c * ipb * 64) * H_ + h) * DH_;
  int grow0 = b * S_ + c * ipb * 64;
  f32x4 zero = {0.f, 0.f, 0.f, 0.f};
  f32x4 acc[4][4];
  for (int i = 0; i < 4; ++i) for (int j = 0; j < 4; ++j) acc[i][j] = zero;
  float k1p[4][4];
  for (int i = 0; i < 4; ++i) for (int r2 = 0; r2 < 4; ++r2) k1p[i][r2] = 0.f;
  float mr = -3.0e38f;
  float vs[16];
  for (int e = 0; e < 16; ++e) vs[e] = 0.f;
  const int r0 = wave * 64;
  bf16x8 pfa_h[2][4], pfa_l[2][4];
  for (int ks = 0; ks < 2; ++ks)
    for (int i = 0; i < 4; ++i) {
      size_t o = (size_t)(r0 + i * 16 + lr) * DH_ + ks * 32 + qd * 8;
      pfa_h[ks][i] = *(const bf16x8*)(ph + o);
      pfa_l[ks][i] = *(const bf16x8*)(pl + o);
    }
  for (int it = 0; it < ipb; ++it) {
    size_t ibase = base0 + (size_t)it * 64 * ROWSTR;
    __syncthreads();  // prev PV (khatT/vTh reads) done before overwrite
    for (int t = 0; t < 2; ++t) {
      int cc = wave + t * 4;
      int rr = cc * 8 + (lane >> 3);
      int csw = (((lane & 7) ^ (rr & 7)) << 3);
      size_t go = ibase + (size_t)rr * ROWSTR + csw;
      lds_load16(khi + go, (void*)&kth[cc * 512]);
      lds_load16(klo + go, (void*)&ktl[cc * 512]);
    }
    if (tid < 64) diagl[tid] = diagk[(size_t)(grow0 + it * 64 + tid) * H_ + h];
    {
      int s = tid >> 2;
      int dv0 = (tid & 3) * 16;
      size_t go = ibase + (size_t)s * ROWSTR + dv0;
      bf16x8 h0 = *(const bf16x8*)(vv + go);
      bf16x8 h1 = *(const bf16x8*)(vv + go + 8);
      for (int e = 0; e < 8; ++e) {
        vTh[vt_idx(dv0 + e, s)] = (u16)h0[e];
        vTh[vt_idx(dv0 + 8 + e, s)] = (u16)h1[e];
        vs[e] += bf2f((u16)h0[e]);
        vs[8 + e] += bf2f((u16)h1[e]);
      }
    }
    __syncthreads();
    f32x4 a1[4][4];
    for (int i = 0; i < 4; ++i) for (int j = 0; j < 4; ++j) a1[i][j] = zero;
    __builtin_amdgcn_s_setprio(1);
    for (int ks = 0; ks < 2; ++ks) {
      bf16x8 bh_[4], bl_[4];
      for (int j = 0; j < 4; ++j) {
        int cof = (ks * 32 + qd * 8) ^ ((lr & 7) << 3);
        bh_[j] = *(const bf16x8*)&kth[(j * 16 + lr) * 64 + cof];
        bl_[j] = *(const bf16x8*)&ktl[(j * 16 + lr) * 64 + cof];
      }
      for (int i = 0; i < 4; ++i)
        for (int j = 0; j < 4; ++j) {
          a1[i][j] = __builtin_amdgcn_mfma_f32_16x16x32_bf16(pfa_h[ks][i], bh_[j], a1[i][j], 0, 0, 0);
          a1[i][j] = __builtin_amdgcn_mfma_f32_16x16x32_bf16(pfa_l[ks][i], bh_[j], a1[i][j], 0, 0, 0);
          a1[i][j] = __builtin_amdgcn_mfma_f32_16x16x32_bf16(pfa_h[ks][i], bl_[j], a1[i][j], 0, 0, 0);
        }
    }
    __builtin_amdgcn_s_setprio(0);
    // chunk max of this 64-row tile
    float mx = -3.0e38f;
    for (int i = 0; i < 4; ++i) for (int j = 0; j < 4; ++j) for (int r2 = 0; r2 < 4; ++r2)
      mx = fmaxf(mx, a1[i][j][r2]);
    for (int m2 = 1; m2 < 64; m2 <<= 1) mx = fmaxf(mx, __shfl_xor(mx, m2, 64));
    if (lane == 0) red[wave] = mx;
    __syncthreads();  // kth/ktl reads done AND red ready -> khatT may overwrite pool
    float cm = nrm * fmaxf(fmaxf(red[0], red[1]), fmaxf(red[2], red[3]));
    if (cm > mr) {
      float sc = __expf(mr - cm);  // first iter: exp(-inf)=0, acc already 0
      for (int i = 0; i < 4; ++i) for (int j = 0; j < 4; ++j)
        for (int r2 = 0; r2 < 4; ++r2) acc[i][j][r2] *= sc;
      for (int i = 0; i < 4; ++i) for (int r2 = 0; r2 < 4; ++r2) k1p[i][r2] *= sc;
      mr = cm;
    }
    for (int i = 0; i < 4; ++i)
      for (int r2 = 0; r2 < 4; ++r2) {
        int r = r0 + i * 16 + qd * 4 + r2;
        for (int j = 0; j < 4; ++j) {
          int s = j * 16 + lr;
          float arg = nrm * a1[i][j][r2] - diagl[s] - mr;  // <= 0 by construction
          u16 khb = f2bf(__expf(arg));
          khatT[r * 72 + s] = khb;
          k1p[i][r2] += bf2f(khb);
        }
      }
    __syncthreads();
    __builtin_amdgcn_s_setprio(1);
    for (int ks = 0; ks < 2; ++ks) {
      bf16x8 af[4], bh_[4];
      for (int i = 0; i < 4; ++i)
        af[i] = *(const bf16x8*)&khatT[(r0 + i * 16 + lr) * 72 + ks * 32 + qd * 8];
      for (int j = 0; j < 4; ++j) {
        int dv = j * 16 + lr;
        bh_[j] = *(const bf16x8*)&vTh[vt_idx(dv, ks * 32 + qd * 8)];
      }
      for (int i = 0; i < 4; ++i)
        for (int j = 0; j < 4; ++j)
          acc[i][j] = __builtin_amdgcn_mfma_f32_16x16x32_bf16(af[i], bh_[j], acc[i][j], 0, 0, 0);
    }
    __builtin_amdgcn_s_setprio(0);
  }
  size_t obase = ((size_t)c * 64 + bh) * R_;
  for (int i = 0; i < 4; ++i)
    for (int j = 0; j < 4; ++j)
      for (int r2 = 0; r2 < 4; ++r2) {
        int r = r0 + i * 16 + qd * 4 + r2;
        int dv = j * 16 + lr;
        pkv[(obase + r) * DH_ + dv] = acc[i][j][r2];
      }
  for (int i = 0; i < 4; ++i)
    for (int r2 = 0; r2 < 4; ++r2) {
      float v = k1p[i][r2];
      v += __shfl_xor(v, 1, 64); v += __shfl_xor(v, 2, 64);
      v += __shfl_xor(v, 4, 64); v += __shfl_xor(v, 8, 64);
      if (lr == 0) pk1[obase + r0 + i * 16 + qd * 4 + r2] = v;
    }
  if (tid == 0) pmc[bid] = mr;
  // v-sum reduce: fbuf aliases pool (khatT dead after final PV)
  __syncthreads();
  float* fbuf = (float*)pool;  // [64 s][64 dv]
  {
    int srow = tid >> 2, g = tid & 3;
    for (int e = 0; e < 16; ++e) fbuf[srow * 64 + g * 16 + e] = vs[e];
  }
  __syncthreads();
  if (tid < 64) {
    float s = 0.f;
    for (int r = 0; r < 64; ++r) s += fbuf[r * 64 + tid];
    pvs[(size_t)bid * 64 + tid] = s;
  }
}

// ---------------- reduce partials -> kvT hi/lo + k1 (ratio + 1e-4 + global max) ----------
// Global max computed per block from pmc (nchunk*64 L2-hot floats) -- no extra dispatch.
__global__ __launch_bounds__(256) void kv_reduce_k(
    const float* __restrict__ pkv, const float* __restrict__ pk1,
    const float* __restrict__ pvs, const float* __restrict__ pmc,
    u16* __restrict__ kvTh, u16* __restrict__ kvTl, float* __restrict__ k1, int nchunk) {
  __shared__ float tile[64][65];
  __shared__ float wbuf[16];
  __shared__ float vbuf[64];
  __shared__ float mgs;
  int bh = blockIdx.x, tl = blockIdx.y, t = threadIdx.x;
  const float ratio = 0.0625f;
  {
    float m = -3.0e38f;
    for (int i = t; i < nchunk * 64; i += 256) m = fmaxf(m, pmc[i]);
    for (int m2 = 1; m2 < 64; m2 <<= 1) m = fmaxf(m, __shfl_xor(m, m2, 64));
    if ((t & 63) == 0) tile[0][t >> 6] = m;
    __syncthreads();
    if (t == 0) mgs = fmaxf(fmaxf(tile[0][0], tile[0][1]), fmaxf(tile[0][2], tile[0][3]));
    __syncthreads();
  }
  float mg0 = mgs;
  if (t < nchunk) wbuf[t] = __expf(pmc[(size_t)t * 64 + bh] - mg0);
  if (t >= 64 && t < 128) {
    int dv = t - 64;
    float s = 0.f;
    for (int c2 = 0; c2 < nchunk; ++c2) s += pvs[((size_t)c2 * 64 + bh) * 64 + dv];
    vbuf[dv] = s;
  }
  __syncthreads();
  if (tl == 0) {
    float s = 0.f;
    for (int c2 = 0; c2 < nchunk; ++c2)
      s += wbuf[c2] * pk1[((size_t)c2 * 64 + bh) * R_ + t];
    k1[(size_t)bh * R_ + t] = ratio * (s + 1e-4f * (float)S_);
  }
  for (int e = 0; e < 16; ++e) {
    int idx = e * 256 + t;
    int rl = idx >> 6, dv = idx & 63;
    float s = 0.f;
    for (int c2 = 0; c2 < nchunk; ++c2)
      s += wbuf[c2] * pkv[(((size_t)c2 * 64 + bh) * R_ + tl * 64 + rl) * DH_ + dv];
    tile[rl][dv] = ratio * (s + 1e-4f * vbuf[dv]);
  }
  __syncthreads();
  for (int e = 0; e < 16; ++e) {
    int idx = e * 256 + t;
    int dv = idx >> 6, rl = idx & 63;
    float s = tile[rl][dv];
    u16 hi = f2bf(s);
    size_t o = ((size_t)bh * DH_ + dv) * R_ + tl * 64 + rl;
    kvTh[o] = hi;
    kvTl[o] = f2bf(s - bf2f(hi));
  }
}

// ---------------- q features + normalize + q_hat x kv ----------------
// qh unions over qth/qtl (dead after a1 phase): 4 blk/CU. Diag precomputed in gemm.
// Denom (q_hat . k1) fused into the exp epilogue.
__global__ __launch_bounds__(256, 4) void q_out_k(
    const u16* __restrict__ qhi, const u16* __restrict__ qlo,
    const u16* __restrict__ ph, const u16* __restrict__ pl,
    const u16* __restrict__ kvTh, const u16* __restrict__ kvTl,
    const float* __restrict__ k1, const float* __restrict__ diagq,
    u16* __restrict__ op) {
  __shared__ __attribute__((aligned(16))) u16 pool[64 * 264];  // qth|qtl then qh
  __shared__ float wrm[4][64];
  __shared__ float dpart[4][64];
  __shared__ float diagl[64];
  __shared__ float dinv[64];
  u16* qth = pool;
  u16* qtl = pool + 4096;
  u16* qh = pool;
  const int tid = threadIdx.x, wave = tid >> 6, lane = tid & 63;
  const int lr = lane & 15, qd = lane >> 4;
  int bid = blockIdx.x;
  int chunk = bid & 63, bh = bid >> 6;
  int b = bh >> 4, h = bh & 15;
  const float nrm = 0.3535533905932738f;
  const float ratio = 0.0625f;
  size_t base = (((size_t)b * S_ + (size_t)chunk * 64) * H_ + h) * DH_;
  const u16* kvThb = kvTh + (size_t)bh * DH_ * R_;
  const u16* kvTlb = kvTl + (size_t)bh * DH_ * R_;
  const float* k1b = k1 + (size_t)bh * R_;
  for (int t = 0; t < 2; ++t) {
    int cc = wave + t * 4;
    int rr = cc * 8 + (lane >> 3);
    int csw = (((lane & 7) ^ (rr & 7)) << 3);
    size_t go = base + (size_t)rr * ROWSTR + csw;
    lds_load16(qhi + go, (void*)&qth[cc * 512]);
    lds_load16(qlo + go, (void*)&qtl[cc * 512]);
  }
  if (tid < 64) diagl[tid] = diagq[(size_t)(b * S_ + chunk * 64 + tid) * H_ + h];
  __syncthreads();
  f32x4 zero = {0.f, 0.f, 0.f, 0.f};
  f32x4 a1[4][4];
  for (int i = 0; i < 4; ++i) for (int j = 0; j < 4; ++j) a1[i][j] = zero;
  const int r0 = wave * 64;
  __builtin_amdgcn_s_setprio(1);
  for (int ks = 0; ks < 2; ++ks) {
    bf16x8 ah[4], al[4], bh_[4], bl_[4];
    for (int i = 0; i < 4; ++i) {
      int cof = (ks * 32 + qd * 8) ^ ((lr & 7) << 3);
      ah[i] = *(const bf16x8*)&qth[(i * 16 + lr) * 64 + cof];
      al[i] = *(const bf16x8*)&qtl[(i * 16 + lr) * 64 + cof];
    }
    for (int j = 0; j < 4; ++j) {
      size_t o = (size_t)(r0 + j * 16 + lr) * DH_ + ks * 32 + qd * 8;
      bh_[j] = *(const bf16x8*)(ph + o);
      bl_[j] = *(const bf16x8*)(pl + o);
    }
    for (int i = 0; i < 4; ++i)
      for (int j = 0; j < 4; ++j) {
        a1[i][j] = __builtin_amdgcn_mfma_f32_16x16x32_bf16(ah[i], bh_[j], a1[i][j], 0, 0, 0);
        a1[i][j] = __builtin_amdgcn_mfma_f32_16x16x32_bf16(al[i], bh_[j], a1[i][j], 0, 0, 0);
        a1[i][j] = __builtin_amdgcn_mfma_f32_16x16x32_bf16(ah[i], bl_[j], a1[i][j], 0, 0, 0);
      }
  }
  __builtin_amdgcn_s_setprio(0);
  for (int i = 0; i < 4; ++i)
    for (int r2 = 0; r2 < 4; ++r2) {
      float v = fmaxf(fmaxf(a1[i][0][r2], a1[i][1][r2]), fmaxf(a1[i][2][r2], a1[i][3][r2]));
      v = fmaxf(v, __shfl_xor(v, 1, 64)); v = fmaxf(v, __shfl_xor(v, 2, 64));
      v = fmaxf(v, __shfl_xor(v, 4, 64)); v = fmaxf(v, __shfl_xor(v, 8, 64));
      if (lr == 0) wrm[wave][i * 16 + qd * 4 + r2] = v;
    }
  __syncthreads();  // qth/qtl dead from here -> qh may overwrite pool
  float k1v[4];
  for (int j = 0; j < 4; ++j) k1v[j] = k1b[r0 + j * 16 + lr];
  for (int i = 0; i < 4; ++i)
    for (int r2 = 0; r2 < 4; ++r2) {
      int s = i * 16 + qd * 4 + r2;
      float rmax = fmaxf(fmaxf(wrm[0][s], wrm[1][s]), fmaxf(wrm[2][s], wrm[3][s]));
      float dg = diagl[s];
      float dsum = 0.f;
      for (int j = 0; j < 4; ++j) {
        float arg = nrm * (a1[i][j][r2] - rmax) - dg;  // <= 0
        float qv = ratio * (__expf(arg) + 1e-4f);
        u16 qvb = f2bf(qv);
        qh[s * 264 + r0 + j * 16 + lr] = qvb;
        dsum += bf2f(qvb) * k1v[j];
      }
      dsum += __shfl_xor(dsum, 1, 64);
      dsum += __shfl_xor(dsum, 2, 64);
      dsum += __shfl_xor(dsum, 4, 64);
      dsum += __shfl_xor(dsum, 8, 64);
      if (lr == 0) dpart[wave][s] = dsum;
    }
  __syncthreads();
  if (tid < 64) {
    float dn = dpart[0][tid] + dpart[1][tid] + dpart[2][tid] + dpart[3][tid];
    dinv[tid] = 1.0f / fmaxf(dn, 1e-35f);
  }
  __syncthreads();
  f32x4 a2[2][2];
  for (int i = 0; i < 2; ++i) for (int j = 0; j < 2; ++j) a2[i][j] = zero;
  const int sw2 = (wave & 1) * 32, dw = (wave >> 1) * 32;
  __builtin_amdgcn_s_setprio(1);
  for (int ks = 0; ks < 8; ++ks) {
    bf16x8 af[2], bh_[2], bl_[2];
    for (int i = 0; i < 2; ++i)
      af[i] = *(const bf16x8*)&qh[(sw2 + i * 16 + lr) * 264 + ks * 32 + qd * 8];
    for (int j = 0; j < 2; ++j) {
      size_t o = (size_t)(dw + j * 16 + lr) * R_ + ks * 32 + qd * 8;
      bh_[j] = *(const bf16x8*)(kvThb + o);
      bl_[j] = *(const bf16x8*)(kvTlb + o);
    }
    for (int i = 0; i < 2; ++i)
      for (int j = 0; j < 2; ++j) {
        a2[i][j] = __builtin_amdgcn_mfma_f32_16x16x32_bf16(af[i], bh_[j], a2[i][j], 0, 0, 0);
        a2[i][j] = __builtin_amdgcn_mfma_f32_16x16x32_bf16(af[i], bl_[j], a2[i][j], 0, 0, 0);
      }
  }
  __builtin_amdgcn_s_setprio(0);
  for (int i = 0; i < 2; ++i)
    for (int r2 = 0; r2 < 4; ++r2) {
      int s = sw2 + i * 16 + qd * 4 + r2;
      float di = dinv[s];
      for (int j = 0; j < 2; ++j) {
        int dv = dw + j * 16 + lr;
        op[base + (size_t)s * ROWSTR + dv] = f2bf(a2[i][j][r2] * di);
      }
    }
}

// ---------------- host-side launch ----------------
extern "C" void kernel_launch(void* const* d_in, const int* in_sizes, int n_in,
                              void* d_out, int out_size, void* d_ws, size_t ws_size,
                              hipStream_t stream) {
  const void* query = d_in[0];
  const void* key   = d_in[1];
  const void* value = d_in[2];
  const void* Wq = d_in[3];
  const void* bq = d_in[4];
  const void* Wk = d_in[5];
  const void* bk = d_in[6];
  const void* Wv = d_in[7];
  const void* bv = d_in[8];
  const void* Wo = d_in[9];
  const void* bo = d_in[10];
  const void* proj = d_in[11];

  char* w = (char*)d_ws;
  const size_t MB = 1024 * 1024;
  u16* WqT_h = (u16*)(w + 0 * MB);
  u16* WqT_l = (u16*)(w + 2 * MB);
  u16* WkT_h = (u16*)(w + 4 * MB);
  u16* WkT_l = (u16*)(w + 6 * MB);
  u16* WvT_h = (u16*)(w + 8 * MB);
  u16* WvT_l = (u16*)(w + 10 * MB);
  u16* WoT_h = (u16*)(w + 12 * MB);
  u16* WoT_l = (u16*)(w + 14 * MB);
  u16* kq_hi = (u16*)(w + 16 * MB);   // 32 MiB: k_hi then q_hi features
  u16* kq_lo = (u16*)(w + 48 * MB);   // 32 MiB
  u16* vop   = (u16*)(w + 80 * MB);   // 32 MiB: v then opre
  float* pvs = (float*)(w + 112 * MB);             // 128 KiB (nchunk=8)
  u16* kvTh  = (u16*)(w + 112 * MB + 512 * 1024);  // 2 MiB
  u16* kvTl  = (u16*)(w + 114 * MB + 512 * 1024);  // 2 MiB
  float* k1  = (float*)(w + 116 * MB + 512 * 1024);        // 64 KiB
  float* pmc = (float*)(w + 116 * MB + 640 * 1024);        // 2 KiB (nchunk*64 floats)
  u16* p_hi  = (u16*)(w + 116 * MB + 768 * 1024);          // 32 KiB
  u16* p_lo  = (u16*)(w + 116 * MB + 832 * 1024);          // 32 KiB
  int* flag  = (int*)(w + 116 * MB + 900 * 1024);          // 4 B
  // union region @117 MB (64 MiB): pkv XOR input hi/lo planes — time-disjoint
  float* pkv  = (float*)(w + 117 * MB);
  u16* inA_hi = (u16*)(w + 117 * MB);
  u16* inA_lo = (u16*)(w + 149 * MB);
  // appended region: diag (K then Q reuse same slot) + pk1
  float* diag_b = (float*)(w + 181 * MB);  // 1 MiB
  float* pk1b   = (float*)(w + 182 * MB);  // 1 MiB
  int nchunk = 8;
  int ipb = 64 / nchunk;

  dtype_probe_k<<<1, 256, 0, stream>>>((const u16*)query, flag);
  transpose4_k<<<dim3(32, 32, 4), dim3(32, 8), 0, stream>>>(
      Wq, Wk, Wv, Wo, WqT_h, WqT_l, WkT_h, WkT_l, WvT_h, WvT_l, WoT_h, WoT_l, flag);
  projcvt_k<<<64, 256, 0, stream>>>(proj, p_hi, p_lo, flag);
  // key path (diag fused into gemm epilogue)
  split_k<1><<<8192, 256, 0, stream>>>(key, inA_hi, inA_lo, flag);
  gemm_k<3, 1><<<dim3(128, 8), 256, 0, stream>>>(inA_hi, inA_lo, WkT_h, WkT_l, bk, kq_hi, kq_lo, diag_b, flag);
  // value path (hi-only)
  split_k<0><<<8192, 256, 0, stream>>>(value, inA_hi, nullptr, flag);
  gemm_k<1, 0><<<dim3(128, 8), 256, 0, stream>>>(inA_hi, nullptr, WvT_h, nullptr, bv, vop, nullptr, nullptr, flag);
  // kv aggregation with online max
  kv_accum_k<<<nchunk * 64, 256, 0, stream>>>(kq_hi, kq_lo, vop, p_hi, p_lo, diag_b, pkv, pk1b, pvs, pmc, ipb);
  kv_reduce_k<<<dim3(64, 4), 256, 0, stream>>>(pkv, pk1b, pvs, pmc, kvTh, kvTl, k1, nchunk);
  // query path (pkv dead after kv_reduce -> union region reusable; diag slot reused)
  split_k<1><<<8192, 256, 0, stream>>>(query, inA_hi, inA_lo, flag);
  gemm_k<3, 1><<<dim3(128, 8), 256, 0, stream>>>(inA_hi, inA_lo, WqT_h, WqT_l, bq, kq_hi, kq_lo, diag_b, flag);
  q_out_k<<<4096, 256, 0, stream>>>(kq_hi, kq_lo, p_hi, p_lo, kvTh, kvTl, k1, diag_b, vop);
  // output projection
  gemm_k<1, 2><<<dim3(128, 8), 256, 0, stream>>>(vop, nullptr, WoT_h, nullptr, bo, d_out, nullptr, nullptr, flag);
}

// Round 5
// 824.206 us; speedup vs baseline: 1.0552x; 1.0552x over previous
//
#include <hip/hip_runtime.h>

typedef unsigned short u16;
typedef unsigned int u32;
typedef __attribute__((ext_vector_type(4))) float f32x4;
typedef __attribute__((ext_vector_type(8))) short bf16x8;

#define B_ 4
#define S_ 4096
#define H_ 16
#define DH_ 64
#define R_ 256
#define DM_ 1024
#define M_ 16384
#define ROWSTR 1024

__device__ __forceinline__ float bf2f(u16 u) {
  union { u32 i; float f; } v; v.i = ((u32)u) << 16; return v.f;
}
__device__ __forceinline__ u16 f2bf(float f) {
  union { float f; u32 i; } v; v.f = f;
  u32 x = v.i;
  return (u16)((x + 0x7FFFu + ((x >> 16) & 1u)) >> 16);
}
// async global->LDS, 16B/lane; dest = wave-uniform base + lane*16 (verified m97 pattern)
__device__ __forceinline__ void lds_load16(const void* g, void* l) {
  __builtin_amdgcn_global_load_lds((__attribute__((address_space(1))) void*)(g),
                                   (__attribute__((address_space(3))) void*)(l), 16, 0, 0);
}
__device__ __forceinline__ int vt_idx(int dv, int s) {  // XOR-swizzled [64][64]
  return dv * 64 + (s ^ (dv & 0x38));
}

// ---------------- dtype probe: bf16 vs f32 underlying data ----------------
__global__ __launch_bounds__(256) void dtype_probe_k(const u16* __restrict__ q,
                                                     int* __restrict__ flag) {
  __shared__ int cnt_s;
  int tid = threadIdx.x;
  if (tid == 0) cnt_s = 0;
  __syncthreads();
  int c = 0;
  for (int i = tid; i < 1024; i += 256) {
    u32 e = ((u32)q[i] >> 7) & 0xFF;
    c += (e >= 134) ? 1 : 0;
  }
  atomicAdd(&cnt_s, c);
  __syncthreads();
  if (tid == 0) flag[0] = (cnt_s > 32) ? 1 : 0;
}

// ---------------- split input [16M elems] -> bf16 hi(/lo) planes ----------------
template <int WLO>
__global__ __launch_bounds__(256) void split_k(const void* __restrict__ src,
                                               u16* __restrict__ hi, u16* __restrict__ lo,
                                               const int* __restrict__ flag) {
  const bool f32m = flag[0] != 0;
  size_t i = ((size_t)blockIdx.x * 256 + threadIdx.x) * 8;
  if (f32m) {
    f32x4 a = *(const f32x4*)((const float*)src + i);
    f32x4 b = *(const f32x4*)((const float*)src + i + 4);
    bf16x8 h, l;
    for (int e = 0; e < 4; ++e) {
      u16 ha = f2bf(a[e]); h[e] = (short)ha; l[e] = (short)f2bf(a[e] - bf2f(ha));
      u16 hb = f2bf(b[e]); h[4 + e] = (short)hb; l[4 + e] = (short)f2bf(b[e] - bf2f(hb));
    }
    *(bf16x8*)(hi + i) = h;
    if (WLO) *(bf16x8*)(lo + i) = l;
  } else {
    bf16x8 h = *(const bf16x8*)((const u16*)src + i);
    *(bf16x8*)(hi + i) = h;
    if (WLO) {
      bf16x8 z = {0, 0, 0, 0, 0, 0, 0, 0};
      *(bf16x8*)(lo + i) = z;
    }
  }
}

// ---------------- transpose+convert 4x [1024][1024] weights -> bf16 hi/lo ----------------
// lo planes written only for z<2 (Wq,Wk); Wv/Wo lo are never consumed.
__global__ __launch_bounds__(256) void transpose4_k(
    const void* __restrict__ s0, const void* __restrict__ s1,
    const void* __restrict__ s2, const void* __restrict__ s3,
    u16* __restrict__ dh0, u16* __restrict__ dl0, u16* __restrict__ dh1, u16* __restrict__ dl1,
    u16* __restrict__ dh2, u16* __restrict__ dl2, u16* __restrict__ dh3, u16* __restrict__ dl3,
    const int* __restrict__ flag) {
  __shared__ float tile[32][33];
  const bool f32m = flag[0] != 0;
  int z = blockIdx.z;
  const void* src = (z == 0) ? s0 : (z == 1) ? s1 : (z == 2) ? s2 : s3;
  u16* dh = (z == 0) ? dh0 : (z == 1) ? dh1 : (z == 2) ? dh2 : dh3;
  u16* dl = (z == 0) ? dl0 : (z == 1) ? dl1 : (z == 2) ? dl2 : dl3;
  int tx = threadIdx.x, ty = threadIdx.y;
  int x0 = blockIdx.x * 32, y0 = blockIdx.y * 32;
  for (int i = ty; i < 32; i += 8) {
    size_t idx = (size_t)(y0 + i) * DM_ + x0 + tx;
    tile[i][tx] = f32m ? ((const float*)src)[idx] : bf2f(((const u16*)src)[idx]);
  }
  __syncthreads();
  for (int i = ty; i < 32; i += 8) {
    float t = tile[tx][i];
    u16 hi = f2bf(t);
    size_t o = (size_t)(x0 + i) * DM_ + y0 + tx;
    dh[o] = hi;
    if (z < 2) dl[o] = f2bf(t - bf2f(hi));
  }
}

// ---------------- convert proj [256*64] -> hi/lo bf16 ----------------
__global__ __launch_bounds__(256) void projcvt_k(const void* __restrict__ p,
                                                 u16* __restrict__ ph, u16* __restrict__ pl,
                                                 const int* __restrict__ flag) {
  const bool f32m = flag[0] != 0;
  int i = blockIdx.x * 256 + threadIdx.x;
  if (i < R_ * DH_) {
    float t = f32m ? ((const float*)p)[i] : bf2f(((const u16*)p)[i]);
    u16 hi = f2bf(t);
    ph[i] = hi;
    pl[i] = f2bf(t - bf2f(hi));
  }
}

// ---------------- 128x128-tile GEMM, C = A[M,K]*Bt[N,K]^T + bias ----------------
// All operands pre-split bf16 planes. PREC 1: hh only. PREC 3: + hl + lh
// (4-plane double-buffered LDS, 48 MFMA per barrier — R3-measured 126us/818TF;
//  occupancy is REGISTER-bound at 2 blk/CU, so 64KB LDS costs nothing).
// OUTMODE: 0 bf16; 1 hi/lo pair + fused diag (Sum q^2 * 0.0625); 2 final.
template <int PREC, int OUTMODE>
__global__ __launch_bounds__(256) void gemm_k(
    const u16* __restrict__ Ah, const u16* __restrict__ Al,
    const u16* __restrict__ Bth, const u16* __restrict__ Btl,
    const void* __restrict__ bias, void* __restrict__ C, u16* __restrict__ Clo,
    float* __restrict__ diag, const int* __restrict__ flag) {
  constexpr int NPL = (PREC == 3) ? 4 : 2;  // planes per buffer: Ah,Bh[,Al,Bl]
  __shared__ __attribute__((aligned(16))) u16 pool[2 * NPL * 4096];
  const bool f32m = flag[0] != 0;
  const int K = DM_, N = DM_;
  const int tid = threadIdx.x, wave = tid >> 6, lane = tid & 63;
  const int lr = lane & 15, qd = lane >> 4;
  const int bm = blockIdx.x, bn = blockIdx.y;
  const int m0 = (wave & 1) * 64, n0 = (wave >> 1) * 64;
  const u16* Abh = Ah + (size_t)bm * 128 * K;
  const u16* Bbh = Bth + (size_t)bn * 128 * K;
  const u16* Abl = (PREC == 3) ? Al + (size_t)bm * 128 * K : nullptr;
  const u16* Bbl = (PREC == 3) ? Btl + (size_t)bn * 128 * K : nullptr;
  f32x4 zero = {0.f, 0.f, 0.f, 0.f};
  f32x4 acc[4][4];
  for (int i = 0; i < 4; ++i) for (int j = 0; j < 4; ++j) acc[i][j] = zero;

#define GEMM_STAGE(bf, kk)                                             \
  do {                                                                 \
    u16* Ph_ = pool + (bf) * (NPL * 4096);                             \
    for (int t_ = 0; t_ < 2; ++t_) {                                   \
      int c_ = wave + t_ * 4;                                          \
      int row_ = c_ * 16 + (lane >> 2);                                \
      int kc_ = (lane & 3) * 8;                                        \
      size_t go_ = (size_t)row_ * K + (kk) + kc_;                      \
      lds_load16(Abh + go_, (void*)&Ph_[c_ * 512]);                    \
      lds_load16(Bbh + go_, (void*)&Ph_[4096 + c_ * 512]);             \
      if (PREC == 3) {                                                 \
        lds_load16(Abl + go_, (void*)&Ph_[2 * 4096 + c_ * 512]);       \
        lds_load16(Bbl + go_, (void*)&Ph_[3 * 4096 + c_ * 512]);       \
      }                                                                \
    }                                                                  \
  } while (0)

  GEMM_STAGE(0, 0);
  int cur = 0;
  for (int k0 = 0; k0 < K; k0 += 32) {
    __syncthreads();  // drains vmcnt(0): buf[cur] staged; prev reads of buf[cur^1] done
    if (k0 + 32 < K) GEMM_STAGE(cur ^ 1, k0 + 32);
    const u16* Ph = pool + cur * (NPL * 4096);
    const u16* Ash = Ph;
    const u16* Bsh = Ph + 4096;
    bf16x8 ah[4], bh[4];
    for (int i = 0; i < 4; ++i) ah[i] = *(const bf16x8*)&Ash[(m0 + i * 16 + lr) * 32 + qd * 8];
    for (int j = 0; j < 4; ++j) bh[j] = *(const bf16x8*)&Bsh[(n0 + j * 16 + lr) * 32 + qd * 8];
    for (int i = 0; i < 4; ++i)
      for (int j = 0; j < 4; ++j)
        acc[i][j] = __builtin_amdgcn_mfma_f32_16x16x32_bf16(ah[i], bh[j], acc[i][j], 0, 0, 0);
    if (PREC == 3) {
      const u16* Asl = Ph + 2 * 4096;
      const u16* Bsl = Ph + 3 * 4096;
      bf16x8 al[4], bl[4];
      for (int i = 0; i < 4; ++i) al[i] = *(const bf16x8*)&Asl[(m0 + i * 16 + lr) * 32 + qd * 8];
      for (int j = 0; j < 4; ++j) bl[j] = *(const bf16x8*)&Bsl[(n0 + j * 16 + lr) * 32 + qd * 8];
      for (int i = 0; i < 4; ++i)
        for (int j = 0; j < 4; ++j) {
          acc[i][j] = __builtin_amdgcn_mfma_f32_16x16x32_bf16(ah[i], bl[j], acc[i][j], 0, 0, 0);
          acc[i][j] = __builtin_amdgcn_mfma_f32_16x16x32_bf16(al[i], bh[j], acc[i][j], 0, 0, 0);
        }
    }
    cur ^= 1;
  }
#undef GEMM_STAGE
  float dq[16];
  if (OUTMODE == 1)
    for (int t = 0; t < 16; ++t) dq[t] = 0.f;
  for (int j = 0; j < 4; ++j) {
    int n = bn * 128 + n0 + j * 16 + lr;
    float bv = f32m ? ((const float*)bias)[n] : bf2f(((const u16*)bias)[n]);
    for (int i = 0; i < 4; ++i) {
      int mr = bm * 128 + m0 + i * 16 + qd * 4;
      for (int r2 = 0; r2 < 4; ++r2) {
        float x = acc[i][j][r2] + bv;
        size_t o = (size_t)(mr + r2) * N + n;
        if (OUTMODE == 0) {
          ((u16*)C)[o] = f2bf(x);
        } else if (OUTMODE == 1) {
          dq[i * 4 + r2] += x * x;
          u16 hi = f2bf(x);
          ((u16*)C)[o] = hi;
          Clo[o] = f2bf(x - bf2f(hi));
        } else {
          if (f32m) ((float*)C)[o] = x;
          else ((u16*)C)[o] = f2bf(x);
        }
      }
    }
  }
  if (OUTMODE == 1) {
    // each (i,r2) row: lanes lr*{j} cover all 64 dh of head h -> shfl-reduce over lr
    int h = (bn * 128 + n0) >> 6;
    for (int t = 0; t < 16; ++t) {
      float v = dq[t];
      v += __shfl_xor(v, 1, 64); v += __shfl_xor(v, 2, 64);
      v += __shfl_xor(v, 4, 64); v += __shfl_xor(v, 8, 64);
      if (lr == 0) {
        int mrow = bm * 128 + m0 + (t >> 2) * 16 + qd * 4 + (t & 3);
        diag[(size_t)mrow * H_ + h] = 0.0625f * v;
      }
    }
  }
}

// ---------------- kv accumulation (online-max; feat_max pass eliminated) ----------------
// Per block: running chunk max mr; acc/k1 rescaled by exp(mr_old-mr_new) on growth.
// Outputs unnormalized: pkv = Sum exp(a-d-mr) x v, pk1 = Sum exp, pvs = Sum v, pmc = mr.
// Final scaling (ratio, 1e-4 regularizer, global max) applied in kv_reduce.
__global__ __launch_bounds__(256) void kv_accum_k(
    const u16* __restrict__ khi, const u16* __restrict__ klo,
    const u16* __restrict__ vv,
    const u16* __restrict__ ph, const u16* __restrict__ pl,
    const float* __restrict__ diagk,
    float* __restrict__ pkv, float* __restrict__ pk1,
    float* __restrict__ pvs, float* __restrict__ pmc, int ipb) {
  __shared__ __attribute__((aligned(16))) u16 pool[256 * 72];  // kth|ktl then khatT then fbuf
  __shared__ __attribute__((aligned(16))) u16 vTh[64 * 64];
  __shared__ float diagl[64];
  __shared__ float red[4];
  u16* kth = pool;
  u16* ktl = pool + 4096;
  u16* khatT = pool;
  const int tid = threadIdx.x, wave = tid >> 6, lane = tid & 63;
  const int lr = lane & 15, qd = lane >> 4;
  int bid = blockIdx.x;
  int bh = bid & 63, c = bid >> 6;
  int b = bh >> 4, h = bh & 15;
  const float nrm = 0.3535533905932738f;
  size_t base0 = (((size_t)b * S_ + (size_t)c * ipb * 64) * H_ + h) * DH_;
  int grow0 = b * S_ + c * ipb * 64;
  f32x4 zero = {0.f, 0.f, 0.f, 0.f};
  f32x4 acc[4][4];
  for (int i = 0; i < 4; ++i) for (int j = 0; j < 4; ++j) acc[i][j] = zero;
  float k1p[4][4];
  for (int i = 0; i < 4; ++i) for (int r2 = 0; r2 < 4; ++r2) k1p[i][r2] = 0.f;
  float mr = -3.0e38f;
  float vs[16];
  for (int e = 0; e < 16; ++e) vs[e] = 0.f;
  const int r0 = wave * 64;
  bf16x8 pfa_h[2][4], pfa_l[2][4];
  for (int ks = 0; ks < 2; ++ks)
    for (int i = 0; i < 4; ++i) {
      size_t o = (size_t)(r0 + i * 16 + lr) * DH_ + ks * 32 + qd * 8;
      pfa_h[ks][i] = *(const bf16x8*)(ph + o);
      pfa_l[ks][i] = *(const bf16x8*)(pl + o);
    }
  for (int it = 0; it < ipb; ++it) {
    size_t ibase = base0 + (size_t)it * 64 * ROWSTR;
    __syncthreads();  // prev PV (khatT/vTh reads) done before overwrite
    for (int t = 0; t < 2; ++t) {
      int cc = wave + t * 4;
      int rr = cc * 8 + (lane >> 3);
      int csw = (((lane & 7) ^ (rr & 7)) << 3);
      size_t go = ibase + (size_t)rr * ROWSTR + csw;
      lds_load16(khi + go, (void*)&kth[cc * 512]);
      lds_load16(klo + go, (void*)&ktl[cc * 512]);
    }
    if (tid < 64) diagl[tid] = diagk[(size_t)(grow0 + it * 64 + tid) * H_ + h];
    {
      int s = tid >> 2;
      int dv0 = (tid & 3) * 16;
      size_t go = ibase + (size_t)s * ROWSTR + dv0;
      bf16x8 h0 = *(const bf16x8*)(vv + go);
      bf16x8 h1 = *(const bf16x8*)(vv + go + 8);
      for (int e = 0; e < 8; ++e) {
        vTh[vt_idx(dv0 + e, s)] = (u16)h0[e];
        vTh[vt_idx(dv0 + 8 + e, s)] = (u16)h1[e];
        vs[e] += bf2f((u16)h0[e]);
        vs[8 + e] += bf2f((u16)h1[e]);
      }
    }
    __syncthreads();
    f32x4 a1[4][4];
    for (int i = 0; i < 4; ++i) for (int j = 0; j < 4; ++j) a1[i][j] = zero;
    __builtin_amdgcn_s_setprio(1);
    for (int ks = 0; ks < 2; ++ks) {
      bf16x8 bh_[4], bl_[4];
      for (int j = 0; j < 4; ++j) {
        int cof = (ks * 32 + qd * 8) ^ ((lr & 7) << 3);
        bh_[j] = *(const bf16x8*)&kth[(j * 16 + lr) * 64 + cof];
        bl_[j] = *(const bf16x8*)&ktl[(j * 16 + lr) * 64 + cof];
      }
      for (int i = 0; i < 4; ++i)
        for (int j = 0; j < 4; ++j) {
          a1[i][j] = __builtin_amdgcn_mfma_f32_16x16x32_bf16(pfa_h[ks][i], bh_[j], a1[i][j], 0, 0, 0);
          a1[i][j] = __builtin_amdgcn_mfma_f32_16x16x32_bf16(pfa_l[ks][i], bh_[j], a1[i][j], 0, 0, 0);
          a1[i][j] = __builtin_amdgcn_mfma_f32_16x16x32_bf16(pfa_h[ks][i], bl_[j], a1[i][j], 0, 0, 0);
        }
    }
    __builtin_amdgcn_s_setprio(0);
    // chunk max of this 64-row tile
    float mx = -3.0e38f;
    for (int i = 0; i < 4; ++i) for (int j = 0; j < 4; ++j) for (int r2 = 0; r2 < 4; ++r2)
      mx = fmaxf(mx, a1[i][j][r2]);
    for (int m2 = 1; m2 < 64; m2 <<= 1) mx = fmaxf(mx, __shfl_xor(mx, m2, 64));
    if (lane == 0) red[wave] = mx;
    __syncthreads();  // kth/ktl reads done AND red ready -> khatT may overwrite pool
    float cm = nrm * fmaxf(fmaxf(red[0], red[1]), fmaxf(red[2], red[3]));
    if (cm > mr) {
      float sc = __expf(mr - cm);  // first iter: exp(-inf)=0, acc already 0
      for (int i = 0; i < 4; ++i) for (int j = 0; j < 4; ++j)
        for (int r2 = 0; r2 < 4; ++r2) acc[i][j][r2] *= sc;
      for (int i = 0; i < 4; ++i) for (int r2 = 0; r2 < 4; ++r2) k1p[i][r2] *= sc;
      mr = cm;
    }
    for (int i = 0; i < 4; ++i)
      for (int r2 = 0; r2 < 4; ++r2) {
        int r = r0 + i * 16 + qd * 4 + r2;
        for (int j = 0; j < 4; ++j) {
          int s = j * 16 + lr;
          float arg = nrm * a1[i][j][r2] - diagl[s] - mr;  // <= 0 by construction
          u16 khb = f2bf(__expf(arg));
          khatT[r * 72 + s] = khb;
          k1p[i][r2] += bf2f(khb);
        }
      }
    __syncthreads();
    __builtin_amdgcn_s_setprio(1);
    for (int ks = 0; ks < 2; ++ks) {
      bf16x8 af[4], bh_[4];
      for (int i = 0; i < 4; ++i)
        af[i] = *(const bf16x8*)&khatT[(r0 + i * 16 + lr) * 72 + ks * 32 + qd * 8];
      for (int j = 0; j < 4; ++j) {
        int dv = j * 16 + lr;
        bh_[j] = *(const bf16x8*)&vTh[vt_idx(dv, ks * 32 + qd * 8)];
      }
      for (int i = 0; i < 4; ++i)
        for (int j = 0; j < 4; ++j)
          acc[i][j] = __builtin_amdgcn_mfma_f32_16x16x32_bf16(af[i], bh_[j], acc[i][j], 0, 0, 0);
    }
    __builtin_amdgcn_s_setprio(0);
  }
  size_t obase = ((size_t)c * 64 + bh) * R_;
  for (int i = 0; i < 4; ++i)
    for (int j = 0; j < 4; ++j)
      for (int r2 = 0; r2 < 4; ++r2) {
        int r = r0 + i * 16 + qd * 4 + r2;
        int dv = j * 16 + lr;
        pkv[(obase + r) * DH_ + dv] = acc[i][j][r2];
      }
  for (int i = 0; i < 4; ++i)
    for (int r2 = 0; r2 < 4; ++r2) {
      float v = k1p[i][r2];
      v += __shfl_xor(v, 1, 64); v += __shfl_xor(v, 2, 64);
      v += __shfl_xor(v, 4, 64); v += __shfl_xor(v, 8, 64);
      if (lr == 0) pk1[obase + r0 + i * 16 + qd * 4 + r2] = v;
    }
  if (tid == 0) pmc[bid] = mr;
  // v-sum reduce: fbuf aliases pool (khatT dead after final PV)
  __syncthreads();
  float* fbuf = (float*)pool;  // [64 s][64 dv]
  {
    int srow = tid >> 2, g = tid & 3;
    for (int e = 0; e < 16; ++e) fbuf[srow * 64 + g * 16 + e] = vs[e];
  }
  __syncthreads();
  if (tid < 64) {
    float s = 0.f;
    for (int r = 0; r < 64; ++r) s += fbuf[r * 64 + tid];
    pvs[(size_t)bid * 64 + tid] = s;
  }
}

// ---------------- reduce partials -> kvT hi/lo + k1 (ratio + 1e-4 + global max) ----------
// Global max computed per block from pmc (nchunk*64 L2-hot floats) -- no extra dispatch.
__global__ __launch_bounds__(256) void kv_reduce_k(
    const float* __restrict__ pkv, const float* __restrict__ pk1,
    const float* __restrict__ pvs, const float* __restrict__ pmc,
    u16* __restrict__ kvTh, u16* __restrict__ kvTl, float* __restrict__ k1, int nchunk) {
  __shared__ float tile[64][65];
  __shared__ float wbuf[16];
  __shared__ float vbuf[64];
  __shared__ float mgs;
  int bh = blockIdx.x, tl = blockIdx.y, t = threadIdx.x;
  const float ratio = 0.0625f;
  {
    float m = -3.0e38f;
    for (int i = t; i < nchunk * 64; i += 256) m = fmaxf(m, pmc[i]);
    for (int m2 = 1; m2 < 64; m2 <<= 1) m = fmaxf(m, __shfl_xor(m, m2, 64));
    if ((t & 63) == 0) tile[0][t >> 6] = m;
    __syncthreads();
    if (t == 0) mgs = fmaxf(fmaxf(tile[0][0], tile[0][1]), fmaxf(tile[0][2], tile[0][3]));
    __syncthreads();
  }
  float mg0 = mgs;
  if (t < nchunk) wbuf[t] = __expf(pmc[(size_t)t * 64 + bh] - mg0);
  if (t >= 64 && t < 128) {
    int dv = t - 64;
    float s = 0.f;
    for (int c2 = 0; c2 < nchunk; ++c2) s += pvs[((size_t)c2 * 64 + bh) * 64 + dv];
    vbuf[dv] = s;
  }
  __syncthreads();
  if (tl == 0) {
    float s = 0.f;
    for (int c2 = 0; c2 < nchunk; ++c2)
      s += wbuf[c2] * pk1[((size_t)c2 * 64 + bh) * R_ + t];
    k1[(size_t)bh * R_ + t] = ratio * (s + 1e-4f * (float)S_);
  }
  for (int e = 0; e < 16; ++e) {
    int idx = e * 256 + t;
    int rl = idx >> 6, dv = idx & 63;
    float s = 0.f;
    for (int c2 = 0; c2 < nchunk; ++c2)
      s += wbuf[c2] * pkv[(((size_t)c2 * 64 + bh) * R_ + tl * 64 + rl) * DH_ + dv];
    tile[rl][dv] = ratio * (s + 1e-4f * vbuf[dv]);
  }
  __syncthreads();
  for (int e = 0; e < 16; ++e) {
    int idx = e * 256 + t;
    int dv = idx >> 6, rl = idx & 63;
    float s = tile[rl][dv];
    u16 hi = f2bf(s);
    size_t o = ((size_t)bh * DH_ + dv) * R_ + tl * 64 + rl;
    kvTh[o] = hi;
    kvTl[o] = f2bf(s - bf2f(hi));
  }
}

// ---------------- q features + normalize + q_hat x kv ----------------
// qh unions over qth/qtl (dead after a1 phase): 4 blk/CU. Diag precomputed in gemm.
// Denom (q_hat . k1) fused into the exp epilogue.
__global__ __launch_bounds__(256, 4) void q_out_k(
    const u16* __restrict__ qhi, const u16* __restrict__ qlo,
    const u16* __restrict__ ph, const u16* __restrict__ pl,
    const u16* __restrict__ kvTh, const u16* __restrict__ kvTl,
    const float* __restrict__ k1, const float* __restrict__ diagq,
    u16* __restrict__ op) {
  __shared__ __attribute__((aligned(16))) u16 pool[64 * 264];  // qth|qtl then qh
  __shared__ float wrm[4][64];
  __shared__ float dpart[4][64];
  __shared__ float diagl[64];
  __shared__ float dinv[64];
  u16* qth = pool;
  u16* qtl = pool + 4096;
  u16* qh = pool;
  const int tid = threadIdx.x, wave = tid >> 6, lane = tid & 63;
  const int lr = lane & 15, qd = lane >> 4;
  int bid = blockIdx.x;
  int chunk = bid & 63, bh = bid >> 6;
  int b = bh >> 4, h = bh & 15;
  const float nrm = 0.3535533905932738f;
  const float ratio = 0.0625f;
  size_t base = (((size_t)b * S_ + (size_t)chunk * 64) * H_ + h) * DH_;
  const u16* kvThb = kvTh + (size_t)bh * DH_ * R_;
  const u16* kvTlb = kvTl + (size_t)bh * DH_ * R_;
  const float* k1b = k1 + (size_t)bh * R_;
  for (int t = 0; t < 2; ++t) {
    int cc = wave + t * 4;
    int rr = cc * 8 + (lane >> 3);
    int csw = (((lane & 7) ^ (rr & 7)) << 3);
    size_t go = base + (size_t)rr * ROWSTR + csw;
    lds_load16(qhi + go, (void*)&qth[cc * 512]);
    lds_load16(qlo + go, (void*)&qtl[cc * 512]);
  }
  if (tid < 64) diagl[tid] = diagq[(size_t)(b * S_ + chunk * 64 + tid) * H_ + h];
  __syncthreads();
  f32x4 zero = {0.f, 0.f, 0.f, 0.f};
  f32x4 a1[4][4];
  for (int i = 0; i < 4; ++i) for (int j = 0; j < 4; ++j) a1[i][j] = zero;
  const int r0 = wave * 64;
  __builtin_amdgcn_s_setprio(1);
  for (int ks = 0; ks < 2; ++ks) {
    bf16x8 ah[4], al[4], bh_[4], bl_[4];
    for (int i = 0; i < 4; ++i) {
      int cof = (ks * 32 + qd * 8) ^ ((lr & 7) << 3);
      ah[i] = *(const bf16x8*)&qth[(i * 16 + lr) * 64 + cof];
      al[i] = *(const bf16x8*)&qtl[(i * 16 + lr) * 64 + cof];
    }
    for (int j = 0; j < 4; ++j) {
      size_t o = (size_t)(r0 + j * 16 + lr) * DH_ + ks * 32 + qd * 8;
      bh_[j] = *(const bf16x8*)(ph + o);
      bl_[j] = *(const bf16x8*)(pl + o);
    }
    for (int i = 0; i < 4; ++i)
      for (int j = 0; j < 4; ++j) {
        a1[i][j] = __builtin_amdgcn_mfma_f32_16x16x32_bf16(ah[i], bh_[j], a1[i][j], 0, 0, 0);
        a1[i][j] = __builtin_amdgcn_mfma_f32_16x16x32_bf16(al[i], bh_[j], a1[i][j], 0, 0, 0);
        a1[i][j] = __builtin_amdgcn_mfma_f32_16x16x32_bf16(ah[i], bl_[j], a1[i][j], 0, 0, 0);
      }
  }
  __builtin_amdgcn_s_setprio(0);
  for (int i = 0; i < 4; ++i)
    for (int r2 = 0; r2 < 4; ++r2) {
      float v = fmaxf(fmaxf(a1[i][0][r2], a1[i][1][r2]), fmaxf(a1[i][2][r2], a1[i][3][r2]));
      v = fmaxf(v, __shfl_xor(v, 1, 64)); v = fmaxf(v, __shfl_xor(v, 2, 64));
      v = fmaxf(v, __shfl_xor(v, 4, 64)); v = fmaxf(v, __shfl_xor(v, 8, 64));
      if (lr == 0) wrm[wave][i * 16 + qd * 4 + r2] = v;
    }
  __syncthreads();  // qth/qtl dead from here -> qh may overwrite pool
  float k1v[4];
  for (int j = 0; j < 4; ++j) k1v[j] = k1b[r0 + j * 16 + lr];
  for (int i = 0; i < 4; ++i)
    for (int r2 = 0; r2 < 4; ++r2) {
      int s = i * 16 + qd * 4 + r2;
      float rmax = fmaxf(fmaxf(wrm[0][s], wrm[1][s]), fmaxf(wrm[2][s], wrm[3][s]));
      float dg = diagl[s];
      float dsum = 0.f;
      for (int j = 0; j < 4; ++j) {
        float arg = nrm * (a1[i][j][r2] - rmax) - dg;  // <= 0
        float qv = ratio * (__expf(arg) + 1e-4f);
        u16 qvb = f2bf(qv);
        qh[s * 264 + r0 + j * 16 + lr] = qvb;
        dsum += bf2f(qvb) * k1v[j];
      }
      dsum += __shfl_xor(dsum, 1, 64);
      dsum += __shfl_xor(dsum, 2, 64);
      dsum += __shfl_xor(dsum, 4, 64);
      dsum += __shfl_xor(dsum, 8, 64);
      if (lr == 0) dpart[wave][s] = dsum;
    }
  __syncthreads();
  if (tid < 64) {
    float dn = dpart[0][tid] + dpart[1][tid] + dpart[2][tid] + dpart[3][tid];
    dinv[tid] = 1.0f / fmaxf(dn, 1e-35f);
  }
  __syncthreads();
  f32x4 a2[2][2];
  for (int i = 0; i < 2; ++i) for (int j = 0; j < 2; ++j) a2[i][j] = zero;
  const int sw2 = (wave & 1) * 32, dw = (wave >> 1) * 32;
  __builtin_amdgcn_s_setprio(1);
  for (int ks = 0; ks < 8; ++ks) {
    bf16x8 af[2], bh_[2], bl_[2];
    for (int i = 0; i < 2; ++i)
      af[i] = *(const bf16x8*)&qh[(sw2 + i * 16 + lr) * 264 + ks * 32 + qd * 8];
    for (int j = 0; j < 2; ++j) {
      size_t o = (size_t)(dw + j * 16 + lr) * R_ + ks * 32 + qd * 8;
      bh_[j] = *(const bf16x8*)(kvThb + o);
      bl_[j] = *(const bf16x8*)(kvTlb + o);
    }
    for (int i = 0; i < 2; ++i)
      for (int j = 0; j < 2; ++j) {
        a2[i][j] = __builtin_amdgcn_mfma_f32_16x16x32_bf16(af[i], bh_[j], a2[i][j], 0, 0, 0);
        a2[i][j] = __builtin_amdgcn_mfma_f32_16x16x32_bf16(af[i], bl_[j], a2[i][j], 0, 0, 0);
      }
  }
  __builtin_amdgcn_s_setprio(0);
  for (int i = 0; i < 2; ++i)
    for (int r2 = 0; r2 < 4; ++r2) {
      int s = sw2 + i * 16 + qd * 4 + r2;
      float di = dinv[s];
      for (int j = 0; j < 2; ++j) {
        int dv = dw + j * 16 + lr;
        op[base + (size_t)s * ROWSTR + dv] = f2bf(a2[i][j][r2] * di);
      }
    }
}

// ---------------- host-side launch ----------------
extern "C" void kernel_launch(void* const* d_in, const int* in_sizes, int n_in,
                              void* d_out, int out_size, void* d_ws, size_t ws_size,
                              hipStream_t stream) {
  const void* query = d_in[0];
  const void* key   = d_in[1];
  const void* value = d_in[2];
  const void* Wq = d_in[3];
  const void* bq = d_in[4];
  const void* Wk = d_in[5];
  const void* bk = d_in[6];
  const void* Wv = d_in[7];
  const void* bv = d_in[8];
  const void* Wo = d_in[9];
  const void* bo = d_in[10];
  const void* proj = d_in[11];

  char* w = (char*)d_ws;
  const size_t MB = 1024 * 1024;
  u16* WqT_h = (u16*)(w + 0 * MB);
  u16* WqT_l = (u16*)(w + 2 * MB);
  u16* WkT_h = (u16*)(w + 4 * MB);
  u16* WkT_l = (u16*)(w + 6 * MB);
  u16* WvT_h = (u16*)(w + 8 * MB);
  u16* WvT_l = (u16*)(w + 10 * MB);
  u16* WoT_h = (u16*)(w + 12 * MB);
  u16* WoT_l = (u16*)(w + 14 * MB);
  u16* kq_hi = (u16*)(w + 16 * MB);   // 32 MiB: k_hi then q_hi features
  u16* kq_lo = (u16*)(w + 48 * MB);   // 32 MiB
  u16* vop   = (u16*)(w + 80 * MB);   // 32 MiB: v then opre
  float* pvs = (float*)(w + 112 * MB);             // 128 KiB (nchunk=8)
  u16* kvTh  = (u16*)(w + 112 * MB + 512 * 1024);  // 2 MiB
  u16* kvTl  = (u16*)(w + 114 * MB + 512 * 1024);  // 2 MiB
  float* k1  = (float*)(w + 116 * MB + 512 * 1024);        // 64 KiB
  float* pmc = (float*)(w + 116 * MB + 640 * 1024);        // 2 KiB (nchunk*64 floats)
  u16* p_hi  = (u16*)(w + 116 * MB + 768 * 1024);          // 32 KiB
  u16* p_lo  = (u16*)(w + 116 * MB + 832 * 1024);          // 32 KiB
  int* flag  = (int*)(w + 116 * MB + 900 * 1024);          // 4 B
  // union region @117 MB (64 MiB): pkv XOR input hi/lo planes — time-disjoint
  float* pkv  = (float*)(w + 117 * MB);
  u16* inA_hi = (u16*)(w + 117 * MB);
  u16* inA_lo = (u16*)(w + 149 * MB);
  // appended region: diag (K then Q reuse same slot) + pk1
  float* diag_b = (float*)(w + 181 * MB);  // 1 MiB
  float* pk1b   = (float*)(w + 182 * MB);  // 1 MiB
  int nchunk = 8;
  int ipb = 64 / nchunk;

  dtype_probe_k<<<1, 256, 0, stream>>>((const u16*)query, flag);
  transpose4_k<<<dim3(32, 32, 4), dim3(32, 8), 0, stream>>>(
      Wq, Wk, Wv, Wo, WqT_h, WqT_l, WkT_h, WkT_l, WvT_h, WvT_l, WoT_h, WoT_l, flag);
  projcvt_k<<<64, 256, 0, stream>>>(proj, p_hi, p_lo, flag);
  // key path (diag fused into gemm epilogue)
  split_k<1><<<8192, 256, 0, stream>>>(key, inA_hi, inA_lo, flag);
  gemm_k<3, 1><<<dim3(128, 8), 256, 0, stream>>>(inA_hi, inA_lo, WkT_h, WkT_l, bk, kq_hi, kq_lo, diag_b, flag);
  // value path (hi-only)
  split_k<0><<<8192, 256, 0, stream>>>(value, inA_hi, nullptr, flag);
  gemm_k<1, 0><<<dim3(128, 8), 256, 0, stream>>>(inA_hi, nullptr, WvT_h, nullptr, bv, vop, nullptr, nullptr, flag);
  // kv aggregation with online max
  kv_accum_k<<<nchunk * 64, 256, 0, stream>>>(kq_hi, kq_lo, vop, p_hi, p_lo, diag_b, pkv, pk1b, pvs, pmc, ipb);
  kv_reduce_k<<<dim3(64, 4), 256, 0, stream>>>(pkv, pk1b, pvs, pmc, kvTh, kvTl, k1, nchunk);
  // query path (pkv dead after kv_reduce -> union region reusable; diag slot reused)
  split_k<1><<<8192, 256, 0, stream>>>(query, inA_hi, inA_lo, flag);
  gemm_k<3, 1><<<dim3(128, 8), 256, 0, stream>>>(inA_hi, inA_lo, WqT_h, WqT_l, bq, kq_hi, kq_lo, diag_b, flag);
  q_out_k<<<4096, 256, 0, stream>>>(kq_hi, kq_lo, p_hi, p_lo, kvTh, kvTl, k1, diag_b, vop);
  // output projection
  gemm_k<1, 2><<<dim3(128, 8), 256, 0, stream>>>(vop, nullptr, WoT_h, nullptr, bo, d_out, nullptr, nullptr, flag);
}